// Round 1
// baseline (15918.146 us; speedup 1.0000x reference)
//
#include <hip/hip_runtime.h>
#include <hip/hip_bf16.h>
#include <stdint.h>

#define NPTS 500000
#define HSIZE (1u << 21)
#define HMASK (HSIZE - 1)
#define FP 72  // LDS row pitch in ushorts (64 + 8 pad -> 2-way max bank aliasing)

typedef __attribute__((ext_vector_type(8))) short short8;
typedef __attribute__((ext_vector_type(4))) float float4v;

__device__ __forceinline__ unsigned short f2b(float f) {
    __hip_bfloat16 h = __float2bfloat16(f);
    return __builtin_bit_cast(unsigned short, h);
}
__device__ __forceinline__ float b2f(unsigned short u) {
    return __builtin_bit_cast(float, ((unsigned)u) << 16);
}

// ---- convert W1, W2 (f32, [s][c][j]) to bf16 transposed [s][j][c] ----
__global__ __launch_bounds__(256) void wconv(const float* __restrict__ W1,
                                             const float* __restrict__ W2,
                                             unsigned short* __restrict__ W1T,
                                             unsigned short* __restrict__ W2T) {
    int i = blockIdx.x * 256 + threadIdx.x;
    if (i >= 3 * 4096) return;
    int s = i >> 12, rem = i & 4095, c = rem >> 6, j = rem & 63;
    W1T[s * 4096 + j * 64 + c] = f2b(W1[i]);
    W2T[s * 4096 + j * 64 + c] = f2b(W2[i]);
}

// ---- per scale: hash-insert voxel keys, count, scatter-add feats ----
// one wave per point: lane 0 inserts, all 64 lanes atomicAdd their channel
__global__ __launch_bounds__(256) void build_vox(const int* __restrict__ coords,
                                                 const float* __restrict__ feats,
                                                 int shift,
                                                 int* __restrict__ hK, int* __restrict__ hV,
                                                 int* __restrict__ gcnt, int* __restrict__ gctr,
                                                 float* __restrict__ gsum) {
    int gw = (blockIdx.x * 256 + threadIdx.x) >> 6;
    int lane = threadIdx.x & 63;
    if (gw >= NPTS) return;
    int gid = -1;
    if (lane == 0) {
        const int* cd = coords + (size_t)gw * 4;
        int key = (((cd[3] * 512 + (cd[0] >> shift)) * 512 + (cd[1] >> shift)) * 512 +
                   (cd[2] >> shift));
        unsigned h = ((unsigned)key * 2654435761u) >> 11;  // top 21 bits
        while (true) {
            int prev = atomicCAS(&hK[h], -1, key);
            if (prev == -1) {
                gid = atomicAdd(gctr, 1);
                atomicExch(&hV[h], gid);
                break;
            }
            if (prev == key) {
                do { gid = atomicAdd(&hV[h], 0); } while (gid == -1);
                break;
            }
            h = (h + 1) & HMASK;
        }
        atomicAdd(&gcnt[gid], 1);
    }
    gid = __shfl(gid, 0);
    atomicAdd(&gsum[(size_t)gid * 64 + lane], feats[(size_t)gw * 64 + lane]);
}

// ---- per scale: 8-corner lookup, exact argmax (first-max), gather mean -> up (bf16)
__global__ __launch_bounds__(256) void devox(const int* __restrict__ coords, int shift,
                                             const int* __restrict__ hK,
                                             const int* __restrict__ hV,
                                             const int* __restrict__ gcnt,
                                             const float* __restrict__ gsum,
                                             unsigned short* __restrict__ up) {
    int gw = (blockIdx.x * 256 + threadIdx.x) >> 6;
    int lane = threadIdx.x & 63;
    if (gw >= NPTS) return;
    const int* cd = coords + (size_t)gw * 4;
    int x = cd[0], y = cd[1], z = cd[2], b = cd[3];
    int vx = x >> shift, vy = y >> shift, vz = z >> shift;
    float w = -1.0f;
    int g = -1;
    if (lane < 8) {
        float inv = 1.0f / (float)(1 << shift);
        float fx = (float)(x - (vx << shift)) * inv;  // exact dyadic
        float fy = (float)(y - (vy << shift)) * inv;
        float fz = (float)(z - (vz << shift)) * inv;
        int bx = (lane >> 2) & 1, by = (lane >> 1) & 1, bz = lane & 1;
        float wx = bx ? fx : 1.0f - fx;
        float wy = by ? fy : 1.0f - fy;
        float wz = bz ? fz : 1.0f - fz;
        w = (wx * wy) * wz;  // same assoc order as jnp.prod
        int key = (((b * 512 + (vx + bx)) * 512 + (vy + by)) * 512 + (vz + bz));
        unsigned h = ((unsigned)key * 2654435761u) >> 11;
        while (true) {
            int k = hK[h];
            if (k == key) { g = hV[h]; break; }
            if (k == -1) { g = -1; break; }
            h = (h + 1) & HMASK;
        }
        if (g < 0) w = 0.0f;
        // argmax with first-occurrence tie-break: strict greater, tie -> smaller j
        int j = lane;
        for (int m = 1; m < 8; m <<= 1) {
            float ow = __shfl_xor(w, m);
            int oj = __shfl_xor(j, m);
            int og = __shfl_xor(g, m);
            if (ow > w || (ow == w && oj < j)) { w = ow; j = oj; g = og; }
        }
    }
    int gstar = __shfl(g, 0);
    float cnt = (float)gcnt[gstar];  // >= 1 always (own voxel exists)
    float val = gsum[(size_t)gstar * 64 + lane] / cnt;
    up[(size_t)gw * 64 + lane] = f2b(val);
}

// ---- fused: 3x (res@W1 -> relu*feats -> @W2 -> relu) + attention combine ----
// block = 256 thr = 4 waves, 64 points/block, MFMA 16x16x32 bf16
__global__ __launch_bounds__(256) void fused_mlp(const float* __restrict__ feats,
                                                 const unsigned short* __restrict__ up,
                                                 const unsigned short* __restrict__ W1T,
                                                 const unsigned short* __restrict__ W2T,
                                                 const float* __restrict__ b1,
                                                 const float* __restrict__ b2,
                                                 const float* __restrict__ Wa,
                                                 const float* __restrict__ ba,
                                                 float* __restrict__ out) {
    __shared__ __align__(16) unsigned short sF[64 * FP];
    __shared__ __align__(16) unsigned short sR[64 * FP];
    __shared__ __align__(16) unsigned short sH[64 * FP];
    __shared__ __align__(16) unsigned short sW1[64 * FP];
    __shared__ __align__(16) unsigned short sW2[64 * FP];

    int tid = threadIdx.x;
    int wave = tid >> 6, lane = tid & 63;
    int ln = lane & 15, quad = lane >> 4;
    int b0 = blockIdx.x * 64;

    // stage feats tile (bf16)
    for (int idx = tid; idx < 4096; idx += 256) {
        int r = idx >> 6, c = idx & 63;
        int n = b0 + r;
        float f = (n < NPTS) ? feats[(size_t)n * 64 + c] : 0.0f;
        sF[r * FP + c] = f2b(f);
    }

    float4v ms[3][4];
    int mrow = wave * 16 + ln;
    int ko = quad * 8;

    for (int s = 0; s < 3; ++s) {
        __syncthreads();
        for (int idx = tid; idx < 4096; idx += 256) {
            int r = idx >> 6, c = idx & 63;
            sW1[r * FP + c] = W1T[s * 4096 + idx];
            sW2[r * FP + c] = W2T[s * 4096 + idx];
        }
        const unsigned short* ups = up + (size_t)s * NPTS * 64;
        for (int idx = tid; idx < 4096; idx += 256) {
            int r = idx >> 6, c = idx & 63;
            int n = b0 + r;
            float u = (n < NPTS) ? b2f(ups[(size_t)n * 64 + c]) : 0.0f;
            sR[r * FP + c] = f2b(b2f(sF[r * FP + c]) - u);
        }
        __syncthreads();

        // GEMM1: H = relu(res @ W1 + b1) * feats
        short8 a0 = *(const short8*)&sR[mrow * FP + ko];
        short8 a1 = *(const short8*)&sR[mrow * FP + 32 + ko];
        for (int nt = 0; nt < 4; ++nt) {
            int ncol = nt * 16 + ln;
            short8 bb0 = *(const short8*)&sW1[ncol * FP + ko];
            short8 bb1 = *(const short8*)&sW1[ncol * FP + 32 + ko];
            float4v c0 = {0.f, 0.f, 0.f, 0.f};
            c0 = __builtin_amdgcn_mfma_f32_16x16x32_bf16(a0, bb0, c0, 0, 0, 0);
            c0 = __builtin_amdgcn_mfma_f32_16x16x32_bf16(a1, bb1, c0, 0, 0, 0);
            float bias = b1[s * 64 + ncol];
            for (int r = 0; r < 4; ++r) {
                int row = wave * 16 + quad * 4 + r;
                float h = fmaxf(c0[r] + bias, 0.0f) * b2f(sF[row * FP + ncol]);
                sH[row * FP + ncol] = f2b(h);
            }
        }
        __syncthreads();

        // GEMM2: ms = relu(H @ W2 + b2)
        short8 h0 = *(const short8*)&sH[mrow * FP + ko];
        short8 h1 = *(const short8*)&sH[mrow * FP + 32 + ko];
        for (int nt = 0; nt < 4; ++nt) {
            int ncol = nt * 16 + ln;
            short8 bb0 = *(const short8*)&sW2[ncol * FP + ko];
            short8 bb1 = *(const short8*)&sW2[ncol * FP + 32 + ko];
            float4v c0 = {0.f, 0.f, 0.f, 0.f};
            c0 = __builtin_amdgcn_mfma_f32_16x16x32_bf16(h0, bb0, c0, 0, 0, 0);
            c0 = __builtin_amdgcn_mfma_f32_16x16x32_bf16(h1, bb1, c0, 0, 0, 0);
            float bias2 = b2[s * 64 + ncol];
            for (int r = 0; r < 4; ++r) c0[r] = fmaxf(c0[r] + bias2, 0.0f);
            ms[s][nt] = c0;
        }
    }

    // attention: att = sigmoid(ssum @ Wa^T + ba); out = sum_s ms_s * att_s
    float4v sa[4];
    for (int nt = 0; nt < 4; ++nt) sa[nt] = ms[0][nt] + ms[1][nt] + ms[2][nt];
    float part[4][3];
    for (int r = 0; r < 4; ++r)
        for (int sh = 0; sh < 3; ++sh) {
            float p = 0.0f;
            for (int nt = 0; nt < 4; ++nt) p += sa[nt][r] * Wa[sh * 64 + nt * 16 + ln];
            part[r][sh] = p;
        }
    for (int m = 1; m < 16; m <<= 1)
        for (int r = 0; r < 4; ++r)
            for (int sh = 0; sh < 3; ++sh) part[r][sh] += __shfl_xor(part[r][sh], m);
    float att[4][3];
    for (int r = 0; r < 4; ++r)
        for (int sh = 0; sh < 3; ++sh)
            att[r][sh] = 1.0f / (1.0f + expf(-(part[r][sh] + ba[sh])));

    for (int nt = 0; nt < 4; ++nt)
        for (int r = 0; r < 4; ++r) {
            int row = wave * 16 + quad * 4 + r;
            int n = b0 + row;
            if (n < NPTS) {
                float o = ms[0][nt][r] * att[r][0] + ms[1][nt][r] * att[r][1] +
                          ms[2][nt][r] * att[r][2];
                out[(size_t)n * 64 + nt * 16 + ln] = o;
            }
        }
}

extern "C" void kernel_launch(void* const* d_in, const int* in_sizes, int n_in,
                              void* d_out, int out_size, void* d_ws, size_t ws_size,
                              hipStream_t stream) {
    const float* feats = (const float*)d_in[0];
    const int* coords = (const int*)d_in[1];
    const float* W1 = (const float*)d_in[2];
    const float* b1 = (const float*)d_in[3];
    const float* W2 = (const float*)d_in[4];
    const float* b2 = (const float*)d_in[5];
    const float* Wa = (const float*)d_in[6];
    const float* ba = (const float*)d_in[7];
    float* out = (float*)d_out;

    char* ws = (char*)d_ws;
    size_t o = 0;
    unsigned short* W1T = (unsigned short*)(ws + o); o += 3 * 4096 * 2;
    unsigned short* W2T = (unsigned short*)(ws + o); o += 3 * 4096 * 2;
    o = (o + 255) & ~(size_t)255;
    unsigned short* up = (unsigned short*)(ws + o); o += (size_t)3 * NPTS * 64 * 2;
    float* gsum = (float*)(ws + o); o += (size_t)NPTS * 64 * 4;
    int* gcnt = (int*)(ws + o); o += (size_t)(NPTS + 1) * 4;
    o = (o + 255) & ~(size_t)255;
    int* hK = (int*)(ws + o); o += (size_t)HSIZE * 4;
    int* hV = (int*)(ws + o); o += (size_t)HSIZE * 4;
    // total ~340 MB

    wconv<<<48, 256, 0, stream>>>(W1, W2, W1T, W2T);

    const int shifts[3] = {1, 2, 3};
    for (int s = 0; s < 3; ++s) {
        hipMemsetAsync(hK, 0xFF, (size_t)HSIZE * 8, stream);  // hK+hV adjacent
        hipMemsetAsync(gcnt, 0, (size_t)(NPTS + 1) * 4, stream);
        hipMemsetAsync(gsum, 0, (size_t)NPTS * 64 * 4, stream);
        build_vox<<<125000, 256, 0, stream>>>(coords, feats, shifts[s], hK, hV, gcnt,
                                              gcnt + NPTS, gsum);
        devox<<<125000, 256, 0, stream>>>(coords, shifts[s], hK, hV, gcnt, gsum,
                                          up + (size_t)s * NPTS * 64);
    }
    fused_mlp<<<7813, 256, 0, stream>>>(feats, up, W1T, W2T, b1, b2, Wa, ba, out);
}

// Round 2
// 2175.410 us; speedup vs baseline: 7.3173x; 7.3173x over previous
//
#include <hip/hip_runtime.h>
#include <hip/hip_bf16.h>
#include <stdint.h>

#define NPTS 500000
#define HSIZE (1u << 20)
#define HMASK (HSIZE - 1)
#define FP 72  // LDS row pitch in ushorts (64 + 8 pad -> 2-way max bank aliasing)

typedef __attribute__((ext_vector_type(8))) short short8;
typedef __attribute__((ext_vector_type(4))) float float4v;

__device__ __forceinline__ unsigned short f2b(float f) {
    __hip_bfloat16 h = __float2bfloat16(f);
    return __builtin_bit_cast(unsigned short, h);
}
__device__ __forceinline__ float b2f(unsigned short u) {
    return __builtin_bit_cast(float, ((unsigned)u) << 16);
}

// ---- convert W1, W2 (f32, [s][c][j]) to bf16 transposed [s][j][c] ----
__global__ __launch_bounds__(256) void wconv(const float* __restrict__ W1,
                                             const float* __restrict__ W2,
                                             unsigned short* __restrict__ W1T,
                                             unsigned short* __restrict__ W2T) {
    int i = blockIdx.x * 256 + threadIdx.x;
    if (i >= 3 * 4096) return;
    int s = i >> 12, rem = i & 4095, c = rem >> 6, j = rem & 63;
    W1T[s * 4096 + j * 64 + c] = f2b(W1[i]);
    W2T[s * 4096 + j * 64 + c] = f2b(W2[i]);
}

// ---- pass 1: hash-insert voxel keys, 1 thread per point.
// Dense gid assignment is wave-aggregated: ONE atomicAdd(gctr, popcount) per
// wave (vs one per insert -> removes the 11.6 ns/op same-address serialization
// that made round-1's build_vox 5.68 ms). hV is finalized before any reader
// kernel launches, so no spin-wait anywhere.
__global__ __launch_bounds__(256) void insert_pts(const int* __restrict__ coords,
                                                  int shift,
                                                  int* __restrict__ hK,
                                                  int* __restrict__ hV,
                                                  int* __restrict__ pslot,
                                                  int* __restrict__ gctr) {
    int i = blockIdx.x * 256 + threadIdx.x;
    bool active = i < NPTS;
    unsigned h = 0;
    bool inserted = false;
    if (active) {
        const int* cd = coords + (size_t)i * 4;
        int key = (((cd[3] * 512 + (cd[0] >> shift)) * 512 + (cd[1] >> shift)) * 512 +
                   (cd[2] >> shift));
        h = ((unsigned)key * 2654435761u) >> 12;  // top 20 bits
        while (true) {
            int prev = atomicCAS(&hK[h], -1, key);
            if (prev == -1) { inserted = true; break; }
            if (prev == key) break;
            h = (h + 1) & HMASK;
        }
        pslot[i] = (int)h;
    }
    unsigned long long mask = __ballot(inserted);
    if (mask) {
        int lane = threadIdx.x & 63;
        int leader = __ffsll((unsigned long long)mask) - 1;
        int base = 0;
        if (lane == leader) base = atomicAdd(gctr, __popcll(mask));
        base = __shfl(base, leader);
        if (inserted)
            hV[h] = base + __popcll(mask & ((1ull << lane) - 1ull));
    }
}

// ---- pass 2: scatter-add feats into per-group sums. one wave per point:
// 64 lanes = 64 channels -> one coalesced 256B atomic burst per point.
__global__ __launch_bounds__(256) void accum(const float* __restrict__ feats,
                                             const int* __restrict__ pslot,
                                             const int* __restrict__ hV,
                                             int* __restrict__ gcnt,
                                             float* __restrict__ gsum) {
    int gw = (blockIdx.x * 256 + threadIdx.x) >> 6;
    int lane = threadIdx.x & 63;
    if (gw >= NPTS) return;
    int gid = 0;
    if (lane == 0) {
        gid = hV[pslot[gw]];
        atomicAdd(&gcnt[gid], 1);
    }
    gid = __shfl(gid, 0);
    atomicAdd(&gsum[(size_t)gid * 64 + lane], feats[(size_t)gw * 64 + lane]);
}

// ---- per scale: 8-corner lookup, exact argmax (first-max), gather mean -> up (bf16)
__global__ __launch_bounds__(256) void devox(const int* __restrict__ coords, int shift,
                                             const int* __restrict__ hK,
                                             const int* __restrict__ hV,
                                             const int* __restrict__ gcnt,
                                             const float* __restrict__ gsum,
                                             unsigned short* __restrict__ up) {
    int gw = (blockIdx.x * 256 + threadIdx.x) >> 6;
    int lane = threadIdx.x & 63;
    if (gw >= NPTS) return;
    const int* cd = coords + (size_t)gw * 4;
    int x = cd[0], y = cd[1], z = cd[2], b = cd[3];
    int vx = x >> shift, vy = y >> shift, vz = z >> shift;
    float w = -1.0f;
    int g = -1;
    if (lane < 8) {
        float inv = 1.0f / (float)(1 << shift);
        float fx = (float)(x - (vx << shift)) * inv;  // exact dyadic
        float fy = (float)(y - (vy << shift)) * inv;
        float fz = (float)(z - (vz << shift)) * inv;
        int bx = (lane >> 2) & 1, by = (lane >> 1) & 1, bz = lane & 1;
        float wx = bx ? fx : 1.0f - fx;
        float wy = by ? fy : 1.0f - fy;
        float wz = bz ? fz : 1.0f - fz;
        w = (wx * wy) * wz;  // same assoc order as jnp.prod
        int key = (((b * 512 + (vx + bx)) * 512 + (vy + by)) * 512 + (vz + bz));
        unsigned h = ((unsigned)key * 2654435761u) >> 12;
        while (true) {
            int k = hK[h];
            if (k == key) { g = hV[h]; break; }
            if (k == -1) { g = -1; break; }
            h = (h + 1) & HMASK;
        }
        if (g < 0) w = 0.0f;
        // argmax with first-occurrence tie-break: strict greater, tie -> smaller j
        int j = lane;
        for (int m = 1; m < 8; m <<= 1) {
            float ow = __shfl_xor(w, m);
            int oj = __shfl_xor(j, m);
            int og = __shfl_xor(g, m);
            if (ow > w || (ow == w && oj < j)) { w = ow; j = oj; g = og; }
        }
    }
    int gstar = __shfl(g, 0);
    float cnt = (float)gcnt[gstar];  // >= 1 always (own voxel exists)
    float val = gsum[(size_t)gstar * 64 + lane] / cnt;
    up[(size_t)gw * 64 + lane] = f2b(val);
}

// ---- fused: 3x (res@W1 -> relu*feats -> @W2 -> relu) + attention combine ----
// block = 256 thr = 4 waves, 64 points/block, MFMA 16x16x32 bf16
__global__ __launch_bounds__(256) void fused_mlp(const float* __restrict__ feats,
                                                 const unsigned short* __restrict__ up,
                                                 const unsigned short* __restrict__ W1T,
                                                 const unsigned short* __restrict__ W2T,
                                                 const float* __restrict__ b1,
                                                 const float* __restrict__ b2,
                                                 const float* __restrict__ Wa,
                                                 const float* __restrict__ ba,
                                                 float* __restrict__ out) {
    __shared__ __align__(16) unsigned short sF[64 * FP];
    __shared__ __align__(16) unsigned short sR[64 * FP];
    __shared__ __align__(16) unsigned short sH[64 * FP];
    __shared__ __align__(16) unsigned short sW1[64 * FP];
    __shared__ __align__(16) unsigned short sW2[64 * FP];

    int tid = threadIdx.x;
    int wave = tid >> 6, lane = tid & 63;
    int ln = lane & 15, quad = lane >> 4;
    int b0 = blockIdx.x * 64;

    // stage feats tile (bf16)
    for (int idx = tid; idx < 4096; idx += 256) {
        int r = idx >> 6, c = idx & 63;
        int n = b0 + r;
        float f = (n < NPTS) ? feats[(size_t)n * 64 + c] : 0.0f;
        sF[r * FP + c] = f2b(f);
    }

    float4v ms[3][4];
    int mrow = wave * 16 + ln;
    int ko = quad * 8;

    for (int s = 0; s < 3; ++s) {
        __syncthreads();
        for (int idx = tid; idx < 4096; idx += 256) {
            int r = idx >> 6, c = idx & 63;
            sW1[r * FP + c] = W1T[s * 4096 + idx];
            sW2[r * FP + c] = W2T[s * 4096 + idx];
        }
        const unsigned short* ups = up + (size_t)s * NPTS * 64;
        for (int idx = tid; idx < 4096; idx += 256) {
            int r = idx >> 6, c = idx & 63;
            int n = b0 + r;
            float u = (n < NPTS) ? b2f(ups[(size_t)n * 64 + c]) : 0.0f;
            sR[r * FP + c] = f2b(b2f(sF[r * FP + c]) - u);
        }
        __syncthreads();

        // GEMM1: H = relu(res @ W1 + b1) * feats
        short8 a0 = *(const short8*)&sR[mrow * FP + ko];
        short8 a1 = *(const short8*)&sR[mrow * FP + 32 + ko];
        for (int nt = 0; nt < 4; ++nt) {
            int ncol = nt * 16 + ln;
            short8 bb0 = *(const short8*)&sW1[ncol * FP + ko];
            short8 bb1 = *(const short8*)&sW1[ncol * FP + 32 + ko];
            float4v c0 = {0.f, 0.f, 0.f, 0.f};
            c0 = __builtin_amdgcn_mfma_f32_16x16x32_bf16(a0, bb0, c0, 0, 0, 0);
            c0 = __builtin_amdgcn_mfma_f32_16x16x32_bf16(a1, bb1, c0, 0, 0, 0);
            float bias = b1[s * 64 + ncol];
            for (int r = 0; r < 4; ++r) {
                int row = wave * 16 + quad * 4 + r;
                float h = fmaxf(c0[r] + bias, 0.0f) * b2f(sF[row * FP + ncol]);
                sH[row * FP + ncol] = f2b(h);
            }
        }
        __syncthreads();

        // GEMM2: ms = relu(H @ W2 + b2)
        short8 h0 = *(const short8*)&sH[mrow * FP + ko];
        short8 h1 = *(const short8*)&sH[mrow * FP + 32 + ko];
        for (int nt = 0; nt < 4; ++nt) {
            int ncol = nt * 16 + ln;
            short8 bb0 = *(const short8*)&sW2[ncol * FP + ko];
            short8 bb1 = *(const short8*)&sW2[ncol * FP + 32 + ko];
            float4v c0 = {0.f, 0.f, 0.f, 0.f};
            c0 = __builtin_amdgcn_mfma_f32_16x16x32_bf16(h0, bb0, c0, 0, 0, 0);
            c0 = __builtin_amdgcn_mfma_f32_16x16x32_bf16(h1, bb1, c0, 0, 0, 0);
            float bias2 = b2[s * 64 + ncol];
            for (int r = 0; r < 4; ++r) c0[r] = fmaxf(c0[r] + bias2, 0.0f);
            ms[s][nt] = c0;
        }
    }

    // attention: att = sigmoid(ssum @ Wa^T + ba); out = sum_s ms_s * att_s
    float4v sa[4];
    for (int nt = 0; nt < 4; ++nt) sa[nt] = ms[0][nt] + ms[1][nt] + ms[2][nt];
    float part[4][3];
    for (int r = 0; r < 4; ++r)
        for (int sh = 0; sh < 3; ++sh) {
            float p = 0.0f;
            for (int nt = 0; nt < 4; ++nt) p += sa[nt][r] * Wa[sh * 64 + nt * 16 + ln];
            part[r][sh] = p;
        }
    for (int m = 1; m < 16; m <<= 1)
        for (int r = 0; r < 4; ++r)
            for (int sh = 0; sh < 3; ++sh) part[r][sh] += __shfl_xor(part[r][sh], m);
    float att[4][3];
    for (int r = 0; r < 4; ++r)
        for (int sh = 0; sh < 3; ++sh)
            att[r][sh] = 1.0f / (1.0f + expf(-(part[r][sh] + ba[sh])));

    for (int nt = 0; nt < 4; ++nt)
        for (int r = 0; r < 4; ++r) {
            int row = wave * 16 + quad * 4 + r;
            int n = b0 + row;
            if (n < NPTS) {
                float o = ms[0][nt][r] * att[r][0] + ms[1][nt][r] * att[r][1] +
                          ms[2][nt][r] * att[r][2];
                out[(size_t)n * 64 + nt * 16 + ln] = o;
            }
        }
}

extern "C" void kernel_launch(void* const* d_in, const int* in_sizes, int n_in,
                              void* d_out, int out_size, void* d_ws, size_t ws_size,
                              hipStream_t stream) {
    const float* feats = (const float*)d_in[0];
    const int* coords = (const int*)d_in[1];
    const float* W1 = (const float*)d_in[2];
    const float* b1 = (const float*)d_in[3];
    const float* W2 = (const float*)d_in[4];
    const float* b2 = (const float*)d_in[5];
    const float* Wa = (const float*)d_in[6];
    const float* ba = (const float*)d_in[7];
    float* out = (float*)d_out;

    char* ws = (char*)d_ws;
    size_t o = 0;
    unsigned short* W1T = (unsigned short*)(ws + o); o += 3 * 4096 * 2;
    unsigned short* W2T = (unsigned short*)(ws + o); o += 3 * 4096 * 2;
    o = (o + 255) & ~(size_t)255;
    unsigned short* up = (unsigned short*)(ws + o); o += (size_t)3 * NPTS * 64 * 2;
    float* gsum = (float*)(ws + o); o += (size_t)NPTS * 64 * 4;
    int* gcnt = (int*)(ws + o); o += (size_t)(NPTS + 1) * 4;
    o = (o + 255) & ~(size_t)255;
    int* hK = (int*)(ws + o); o += (size_t)HSIZE * 4;
    int* hV = (int*)(ws + o); o += (size_t)HSIZE * 4;
    int* pslot = (int*)(ws + o); o += (size_t)NPTS * 4;
    // total ~332 MB

    wconv<<<48, 256, 0, stream>>>(W1, W2, W1T, W2T);

    const int shifts[3] = {1, 2, 3};
    for (int s = 0; s < 3; ++s) {
        hipMemsetAsync(hK, 0xFF, (size_t)HSIZE * 4, stream);
        hipMemsetAsync(gcnt, 0, (size_t)(NPTS + 1) * 4, stream);
        hipMemsetAsync(gsum, 0, (size_t)NPTS * 64 * 4, stream);
        insert_pts<<<(NPTS + 255) / 256, 256, 0, stream>>>(coords, shifts[s], hK, hV,
                                                           pslot, gcnt + NPTS);
        accum<<<125000, 256, 0, stream>>>(feats, pslot, hV, gcnt, gsum);
        devox<<<125000, 256, 0, stream>>>(coords, shifts[s], hK, hV, gcnt, gsum,
                                          up + (size_t)s * NPTS * 64);
    }
    fused_mlp<<<7813, 256, 0, stream>>>(feats, up, W1T, W2T, b1, b2, Wa, ba, out);
}

// Round 3
// 1326.498 us; speedup vs baseline: 12.0001x; 1.6400x over previous
//
#include <hip/hip_runtime.h>
#include <hip/hip_bf16.h>
#include <stdint.h>

#define NPTS 500000
#define HSIZE (1u << 20)
#define HMASK (HSIZE - 1)
#define FP 72  // sH row pitch in ushorts: 144B rows -> 16B-aligned b128 reads, 2-way-free read banks

typedef __attribute__((ext_vector_type(8))) short short8;
typedef __attribute__((ext_vector_type(4))) float float4v;

__device__ __forceinline__ unsigned short f2b(float f) {
    __hip_bfloat16 h = __float2bfloat16(f);
    return __builtin_bit_cast(unsigned short, h);
}
__device__ __forceinline__ float b2f(unsigned short u) {
    return __builtin_bit_cast(float, ((unsigned)u) << 16);
}

// ---- convert W1, W2 (f32, [s][c][j]) to bf16 transposed [s][j][c]; zero gctr ----
__global__ __launch_bounds__(256) void wconv(const float* __restrict__ W1,
                                             const float* __restrict__ W2,
                                             unsigned short* __restrict__ W1T,
                                             unsigned short* __restrict__ W2T,
                                             int* __restrict__ gctr) {
    int i = blockIdx.x * 256 + threadIdx.x;
    if (i < 192) gctr[i] = 0;
    if (i >= 3 * 4096) return;
    int s = i >> 12, rem = i & 4095, c = rem >> 6, j = rem & 63;
    W1T[s * 4096 + j * 64 + c] = f2b(W1[i]);
    W2T[s * 4096 + j * 64 + c] = f2b(W2[i]);
}

// ---- all 3 scales: hash-insert + per-slot linked list + wave-aggregated dense gid ----
__global__ __launch_bounds__(256) void insert3(const int* __restrict__ coords,
                                               int* __restrict__ hK, int* __restrict__ head,
                                               int* __restrict__ hV, int* __restrict__ next,
                                               int* __restrict__ gctr) {
    const int BPS = (NPTS + 255) / 256;  // 1954
    int s = blockIdx.x / BPS;
    int i = (blockIdx.x % BPS) * 256 + threadIdx.x;
    int shift = s + 1;
    int* hKs = hK + (size_t)s * HSIZE;
    int* heads = head + (size_t)s * HSIZE;
    int* hVs = hV + (size_t)s * HSIZE;
    int* nexts = next + (size_t)s * NPTS;
    bool active = i < NPTS;
    unsigned h = 0;
    bool inserted = false;
    if (active) {
        int4 cd = ((const int4*)coords)[i];
        int key = (((cd.w * 512 + (cd.x >> shift)) * 512 + (cd.y >> shift)) * 512 +
                   (cd.z >> shift));
        h = ((unsigned)key * 2654435761u) >> 12;  // top 20 bits
        while (true) {
            int prev = atomicCAS(&hKs[h], -1, key);
            if (prev == -1) { inserted = true; break; }
            if (prev == key) break;
            h = (h + 1) & HMASK;
        }
        nexts[i] = atomicExch(&heads[h], i);
    }
    unsigned long long mask = __ballot(inserted);
    if (mask) {
        int lane = threadIdx.x & 63;
        int leader = __ffsll((unsigned long long)mask) - 1;
        int base = 0;
        if (lane == leader) base = atomicAdd(&gctr[s * 64], __popcll(mask));
        base = __shfl(base, leader);
        if (inserted) hVs[h] = base + __popcll(mask & ((1ull << lane) - 1ull));
    }
}

// ---- all 3 scales: one wave per slot, walk chain, mean -> bf16 vmean[gid] ----
__global__ __launch_bounds__(1024) void reduce3(const float* __restrict__ feats,
                                                const int* __restrict__ head,
                                                const int* __restrict__ next,
                                                const int* __restrict__ hV,
                                                unsigned short* __restrict__ vmean) {
    int gw = blockIdx.x * 16 + (threadIdx.x >> 6);  // global wave = slot index over 3*HSIZE
    int lane = threadIdx.x & 63;
    int s = gw >> 20;
    unsigned slot = (unsigned)gw & HMASK;
    int i = head[(size_t)s * HSIZE + slot];  // wave-uniform broadcast load
    if (i < 0) return;
    const int* nexts = next + (size_t)s * NPTS;
    float sum = 0.0f;
    int cnt = 0;
    while (i >= 0) {
        sum += feats[(size_t)i * 64 + lane];
        cnt++;
        i = nexts[i];
    }
    int gid = hV[(size_t)s * HSIZE + slot];
    vmean[((size_t)s * NPTS + gid) * 64 + lane] = f2b(sum / (float)cnt);
}

// ---- all 3 scales: 8 corners (8 pts/wave), exact first-max argmax, write winning gid ----
__global__ __launch_bounds__(256) void argmax3(const int* __restrict__ coords,
                                               const int* __restrict__ hK,
                                               const int* __restrict__ hV,
                                               int* __restrict__ idx) {
    const int PPB = 32;                 // points per block (256 thr / 8 corners)
    const int BPS = NPTS / PPB;         // 15625 exactly
    int s = blockIdx.x / BPS;
    int p = (blockIdx.x % BPS) * PPB + (threadIdx.x >> 3);
    int corner = threadIdx.x & 7;
    int shift = s + 1;
    const int* hKs = hK + (size_t)s * HSIZE;
    const int* hVs = hV + (size_t)s * HSIZE;
    int4 cd = ((const int4*)coords)[p];
    int vx = cd.x >> shift, vy = cd.y >> shift, vz = cd.z >> shift;
    float inv = 1.0f / (float)(1 << shift);
    float fx = (float)(cd.x - (vx << shift)) * inv;  // exact dyadic
    float fy = (float)(cd.y - (vy << shift)) * inv;
    float fz = (float)(cd.z - (vz << shift)) * inv;
    int bx = (corner >> 2) & 1, by = (corner >> 1) & 1, bz = corner & 1;
    float wx = bx ? fx : 1.0f - fx;
    float wy = by ? fy : 1.0f - fy;
    float wz = bz ? fz : 1.0f - fz;
    float w = (wx * wy) * wz;  // same assoc order as jnp.prod
    int key = (((cd.w * 512 + (vx + bx)) * 512 + (vy + by)) * 512 + (vz + bz));
    unsigned h = ((unsigned)key * 2654435761u) >> 12;
    int g = -1;
    while (true) {
        int k = hKs[h];
        if (k == key) { g = hVs[h]; break; }
        if (k == -1) break;
        h = (h + 1) & HMASK;
    }
    if (g < 0) w = 0.0f;
    // first-occurrence argmax: strict greater, tie -> smaller corner. xor 1/2/4 stays in group.
    int j = corner;
    for (int m = 1; m < 8; m <<= 1) {
        float ow = __shfl_xor(w, m);
        int oj = __shfl_xor(j, m);
        int og = __shfl_xor(g, m);
        if (ow > w || (ow == w && oj < j)) { w = ow; j = oj; g = og; }
    }
    if (corner == 0) idx[(size_t)s * NPTS + p] = g;
}

// ---- fused: gather vmean + 3x (res@W1 -> relu*feats -> @W2 -> relu) + attention ----
// 256 thr = 4 waves, 64 points/block. All fragments loaded direct from global in
// MFMA layout (A: lane=(quad,ln) holds row ln, k=quad*8..+8). sH is wave-private
// (each wave's 16 rows) -> no __syncthreads anywhere.
__global__ __launch_bounds__(256) void fused_mlp(const float* __restrict__ feats,
                                                 const unsigned short* __restrict__ vmean,
                                                 const int* __restrict__ idx,
                                                 const unsigned short* __restrict__ W1T,
                                                 const unsigned short* __restrict__ W2T,
                                                 const float* __restrict__ b1,
                                                 const float* __restrict__ b2,
                                                 const float* __restrict__ Wa,
                                                 const float* __restrict__ ba,
                                                 float* __restrict__ out) {
    __shared__ __align__(16) unsigned short sH[4][16 * FP];

    int tid = threadIdx.x;
    int wave = tid >> 6, lane = tid & 63;
    int ln = lane & 15, quad = lane >> 4, ko = quad * 8;
    int b0 = blockIdx.x * 64;
    int mrow = wave * 16 + ln;
    int nA = b0 + mrow;
    bool vA = nA < NPTS;

    // A-fragment feats rows (f32), reused across scales
    float fA0[8], fA1[8];
    {
        const float* fr = feats + (size_t)(vA ? nA : 0) * 64;
#pragma unroll
        for (int j = 0; j < 8; ++j) { fA0[j] = fr[ko + j]; fA1[j] = fr[32 + ko + j]; }
    }
    // C-layout feats multipliers (row=wave*16+quad*4+r, col=nt*16+ln)
    float fC[4][4];
#pragma unroll
    for (int r = 0; r < 4; ++r) {
        int n = b0 + wave * 16 + quad * 4 + r;
        const float* fp = feats + (size_t)(n < NPTS ? n : 0) * 64;
#pragma unroll
        for (int nt = 0; nt < 4; ++nt) fC[nt][r] = (n < NPTS) ? fp[nt * 16 + ln] : 0.0f;
    }

    float4v ms[3][4];
    unsigned short* sHw = &sH[wave][0];

    for (int s = 0; s < 3; ++s) {
        // residual A-fragments: res = feats - vmean[gid]  (vmean row = 16B contiguous/lane)
        int g = vA ? idx[(size_t)s * NPTS + nA] : 0;
        const unsigned short* vr = vmean + ((size_t)s * NPTS + g) * 64;
        short8 u0 = *(const short8*)&vr[ko];
        short8 u1 = *(const short8*)&vr[32 + ko];
        short8 a0, a1;
#pragma unroll
        for (int j = 0; j < 8; ++j) {
            float r0 = vA ? fA0[j] - b2f((unsigned short)u0[j]) : 0.0f;
            float r1 = vA ? fA1[j] - b2f((unsigned short)u1[j]) : 0.0f;
            a0[j] = (short)f2b(r0);
            a1[j] = (short)f2b(r1);
        }

        // GEMM1: H = relu(res @ W1 + b1) * feats   (weights direct from global, L1-hot)
#pragma unroll
        for (int nt = 0; nt < 4; ++nt) {
            int ncol = nt * 16 + ln;
            const unsigned short* w1r = W1T + s * 4096 + ncol * 64;
            short8 bb0 = *(const short8*)&w1r[ko];
            short8 bb1 = *(const short8*)&w1r[32 + ko];
            float4v c = {0.f, 0.f, 0.f, 0.f};
            c = __builtin_amdgcn_mfma_f32_16x16x32_bf16(a0, bb0, c, 0, 0, 0);
            c = __builtin_amdgcn_mfma_f32_16x16x32_bf16(a1, bb1, c, 0, 0, 0);
            float bias = b1[s * 64 + ncol];
#pragma unroll
            for (int r = 0; r < 4; ++r) {
                float hv = fmaxf(c[r] + bias, 0.0f) * fC[nt][r];
                sHw[(quad * 4 + r) * FP + ncol] = f2b(hv);
            }
        }
        __threadfence_block();  // order wave-private LDS write -> read (no cross-wave dep)

        // GEMM2: ms = relu(H @ W2 + b2)
        short8 h0 = *(const short8*)&sHw[ln * FP + ko];
        short8 h1 = *(const short8*)&sHw[ln * FP + 32 + ko];
#pragma unroll
        for (int nt = 0; nt < 4; ++nt) {
            int ncol = nt * 16 + ln;
            const unsigned short* w2r = W2T + s * 4096 + ncol * 64;
            short8 bb0 = *(const short8*)&w2r[ko];
            short8 bb1 = *(const short8*)&w2r[32 + ko];
            float4v c = {0.f, 0.f, 0.f, 0.f};
            c = __builtin_amdgcn_mfma_f32_16x16x32_bf16(h0, bb0, c, 0, 0, 0);
            c = __builtin_amdgcn_mfma_f32_16x16x32_bf16(h1, bb1, c, 0, 0, 0);
            float bias2 = b2[s * 64 + ncol];
#pragma unroll
            for (int r = 0; r < 4; ++r) c[r] = fmaxf(c[r] + bias2, 0.0f);
            ms[s][nt] = c;
        }
    }

    // attention: att = sigmoid((ms0+ms1+ms2) @ Wa^T + ba); out = sum_s ms_s * att_s
    float4v sa[4];
#pragma unroll
    for (int nt = 0; nt < 4; ++nt) sa[nt] = ms[0][nt] + ms[1][nt] + ms[2][nt];
    float part[4][3];
#pragma unroll
    for (int r = 0; r < 4; ++r)
#pragma unroll
        for (int sh = 0; sh < 3; ++sh) {
            float p = 0.0f;
#pragma unroll
            for (int nt = 0; nt < 4; ++nt) p += sa[nt][r] * Wa[sh * 64 + nt * 16 + ln];
            part[r][sh] = p;
        }
    for (int m = 1; m < 16; m <<= 1)
#pragma unroll
        for (int r = 0; r < 4; ++r)
#pragma unroll
            for (int sh = 0; sh < 3; ++sh) part[r][sh] += __shfl_xor(part[r][sh], m);
    float att[4][3];
#pragma unroll
    for (int r = 0; r < 4; ++r)
#pragma unroll
        for (int sh = 0; sh < 3; ++sh)
            att[r][sh] = 1.0f / (1.0f + expf(-(part[r][sh] + ba[sh])));

#pragma unroll
    for (int nt = 0; nt < 4; ++nt)
#pragma unroll
        for (int r = 0; r < 4; ++r) {
            int n = b0 + wave * 16 + quad * 4 + r;
            if (n < NPTS) {
                float o = ms[0][nt][r] * att[r][0] + ms[1][nt][r] * att[r][1] +
                          ms[2][nt][r] * att[r][2];
                out[(size_t)n * 64 + nt * 16 + ln] = o;
            }
        }
}

extern "C" void kernel_launch(void* const* d_in, const int* in_sizes, int n_in,
                              void* d_out, int out_size, void* d_ws, size_t ws_size,
                              hipStream_t stream) {
    const float* feats = (const float*)d_in[0];
    const int* coords = (const int*)d_in[1];
    const float* W1 = (const float*)d_in[2];
    const float* b1 = (const float*)d_in[3];
    const float* W2 = (const float*)d_in[4];
    const float* b2 = (const float*)d_in[5];
    const float* Wa = (const float*)d_in[6];
    const float* ba = (const float*)d_in[7];
    float* out = (float*)d_out;

    char* ws = (char*)d_ws;
    size_t o = 0;
    unsigned short* W1T = (unsigned short*)(ws + o); o += 3 * 4096 * 2;
    unsigned short* W2T = (unsigned short*)(ws + o); o += 3 * 4096 * 2;
    o = (o + 255) & ~(size_t)255;
    unsigned short* vmean = (unsigned short*)(ws + o); o += (size_t)3 * NPTS * 64 * 2;
    int* idx = (int*)(ws + o); o += (size_t)3 * NPTS * 4;
    int* next = (int*)(ws + o); o += (size_t)3 * NPTS * 4;
    o = (o + 255) & ~(size_t)255;
    int* hK = (int*)(ws + o); o += (size_t)3 * HSIZE * 4;
    int* head = (int*)(ws + o); o += (size_t)3 * HSIZE * 4;  // contiguous with hK
    int* hV = (int*)(ws + o); o += (size_t)3 * HSIZE * 4;
    int* gctr = (int*)(ws + o); o += 192 * 4;
    // total ~229 MB

    wconv<<<48, 256, 0, stream>>>(W1, W2, W1T, W2T, gctr);
    hipMemsetAsync(hK, 0xFF, (size_t)6 * HSIZE * 4, stream);  // hK + head in one memset

    const int BPS = (NPTS + 255) / 256;
    insert3<<<3 * BPS, 256, 0, stream>>>(coords, hK, head, hV, next, gctr);
    reduce3<<<3 * HSIZE / 16, 1024, 0, stream>>>(feats, head, next, hV, vmean);
    argmax3<<<3 * (NPTS / 32), 256, 0, stream>>>(coords, hK, hV, idx);
    fused_mlp<<<(NPTS + 63) / 64, 256, 0, stream>>>(feats, vmean, idx, W1T, W2T, b1, b2,
                                                    Wa, ba, out);
}

// Round 4
// 1185.164 us; speedup vs baseline: 13.4312x; 1.1193x over previous
//
#include <hip/hip_runtime.h>
#include <hip/hip_bf16.h>
#include <stdint.h>

#define NPTS 500000
#define HSIZE (1u << 20)
#define HMASK (HSIZE - 1)
#define FP 72  // sH row pitch in ushorts: 144B rows -> 16B-aligned b128 reads, 2-way-free banks

typedef __attribute__((ext_vector_type(8))) short short8;
typedef __attribute__((ext_vector_type(4))) float float4v;

__device__ __forceinline__ unsigned short f2b(float f) {
    __hip_bfloat16 h = __float2bfloat16(f);
    return __builtin_bit_cast(unsigned short, h);
}
__device__ __forceinline__ float b2f(unsigned short u) {
    return __builtin_bit_cast(float, ((unsigned)u) << 16);
}

// ---- convert W1, W2 (f32, [s][c][j]) to bf16 transposed [s][j][c]; zero gctr ----
__global__ __launch_bounds__(256) void wconv(const float* __restrict__ W1,
                                             const float* __restrict__ W2,
                                             unsigned short* __restrict__ W1T,
                                             unsigned short* __restrict__ W2T,
                                             int* __restrict__ gctr) {
    int i = blockIdx.x * 256 + threadIdx.x;
    if (i < 192) gctr[i] = 0;
    if (i >= 3 * 4096) return;
    int s = i >> 12, rem = i & 4095, c = rem >> 6, j = rem & 63;
    W1T[s * 4096 + j * 64 + c] = f2b(W1[i]);
    W2T[s * 4096 + j * 64 + c] = f2b(W2[i]);
}

// ---- all 3 scales: 64-bit (key,gid) hash insert + per-slot chain + compact slot list ----
// Dense gid via wave-aggregated atomicAdd; CAS winner also records cslot[gid]=slot so
// the reducer can enumerate exactly the non-empty groups (no dead waves).
__global__ __launch_bounds__(256) void insert3(const int* __restrict__ coords,
                                               unsigned long long* __restrict__ hKV,
                                               int* __restrict__ head,
                                               int* __restrict__ next,
                                               int* __restrict__ cslot,
                                               int* __restrict__ gctr) {
    const int BPS = (NPTS + 255) / 256;  // 1954
    int s = blockIdx.x / BPS;
    int i = (blockIdx.x % BPS) * 256 + threadIdx.x;
    int shift = s + 1;
    unsigned long long* hs = hKV + (size_t)s * HSIZE;
    int* heads = head + (size_t)s * HSIZE;
    int* nexts = next + (size_t)s * NPTS;
    bool active = i < NPTS;
    unsigned h = 0;
    bool inserted = false;
    if (active) {
        int4 cd = ((const int4*)coords)[i];
        int key = (((cd.w * 512 + (cd.x >> shift)) * 512 + (cd.y >> shift)) * 512 +
                   (cd.z >> shift));
        unsigned long long want = (unsigned long long)(unsigned)key | 0xFFFFFFFF00000000ull;
        h = ((unsigned)key * 2654435761u) >> 12;  // top 20 bits
        while (true) {
            unsigned long long prev = atomicCAS(&hs[h], ~0ull, want);
            if (prev == ~0ull) { inserted = true; break; }
            if ((int)(prev & 0xFFFFFFFFull) == key) break;
            h = (h + 1) & HMASK;
        }
        nexts[i] = atomicExch(&heads[h], i);
    }
    unsigned long long mask = __ballot(inserted);
    if (mask) {
        int lane = threadIdx.x & 63;
        int leader = __ffsll((unsigned long long)mask) - 1;
        int base = 0;
        if (lane == leader) base = atomicAdd(&gctr[s * 64], __popcll(mask));
        base = __shfl(base, leader);
        if (inserted) {
            int gid = base + __popcll(mask & ((1ull << lane) - 1ull));
            ((int*)&hs[h])[1] = gid;  // high word; slot can never be CAS'd again
            cslot[(size_t)s * NPTS + gid] = (int)h;
        }
    }
}

// ---- all 3 scales: one wave PER GROUP (compact gid enumeration), walk chain, mean ----
__global__ __launch_bounds__(256) void reduce3(const float* __restrict__ feats,
                                               const int* __restrict__ head,
                                               const int* __restrict__ next,
                                               const int* __restrict__ cslot,
                                               const int* __restrict__ gctr,
                                               unsigned short* __restrict__ vmean) {
    int gw = (blockIdx.x * 256 + threadIdx.x) >> 6;  // 0 .. 3*NPTS
    int lane = threadIdx.x & 63;
    int s = gw / NPTS;
    int gid = gw - s * NPTS;
    if (gid >= gctr[s * 64]) return;
    int slot = cslot[(size_t)s * NPTS + gid];
    int i = head[(size_t)s * HSIZE + slot];
    const int* nexts = next + (size_t)s * NPTS;
    float sum = 0.0f;
    int cnt = 0;
    while (i >= 0) {
        sum += feats[(size_t)i * 64 + lane];
        cnt++;
        i = nexts[i];
    }
    vmean[((size_t)s * NPTS + gid) * 64 + lane] = f2b(sum / (float)cnt);
}

// ---- all 3 scales: 8 corners (8 pts/wave), exact first-max argmax, write winning gid ----
__global__ __launch_bounds__(256) void argmax3(const int* __restrict__ coords,
                                               const int2* __restrict__ hKV,
                                               int* __restrict__ idx) {
    const int PPB = 32;                 // points per block (256 thr / 8 corners)
    const int BPS = NPTS / PPB;         // 15625 exactly
    int s = blockIdx.x / BPS;
    int p = (blockIdx.x % BPS) * PPB + (threadIdx.x >> 3);
    int corner = threadIdx.x & 7;
    int shift = s + 1;
    const int2* hs = hKV + (size_t)s * HSIZE;
    int4 cd = ((const int4*)coords)[p];
    int vx = cd.x >> shift, vy = cd.y >> shift, vz = cd.z >> shift;
    float inv = 1.0f / (float)(1 << shift);
    float fx = (float)(cd.x - (vx << shift)) * inv;  // exact dyadic
    float fy = (float)(cd.y - (vy << shift)) * inv;
    float fz = (float)(cd.z - (vz << shift)) * inv;
    int bx = (corner >> 2) & 1, by = (corner >> 1) & 1, bz = corner & 1;
    float wx = bx ? fx : 1.0f - fx;
    float wy = by ? fy : 1.0f - fy;
    float wz = bz ? fz : 1.0f - fz;
    float w = (wx * wy) * wz;  // same assoc order as jnp.prod
    int key = (((cd.w * 512 + (vx + bx)) * 512 + (vy + by)) * 512 + (vz + bz));
    unsigned h = ((unsigned)key * 2654435761u) >> 12;
    int g = -1;
    while (true) {
        int2 kv = hs[h];                // key + gid in ONE 8B load
        if (kv.x == key) { g = kv.y; break; }
        if (kv.x == -1) break;
        h = (h + 1) & HMASK;
    }
    if (g < 0) w = 0.0f;
    // first-occurrence argmax: strict greater, tie -> smaller corner. xor 1/2/4 stays in group.
    int j = corner;
    for (int m = 1; m < 8; m <<= 1) {
        float ow = __shfl_xor(w, m);
        int oj = __shfl_xor(j, m);
        int og = __shfl_xor(g, m);
        if (ow > w || (ow == w && oj < j)) { w = ow; j = oj; g = og; }
    }
    if (corner == 0) idx[(size_t)s * NPTS + p] = g;
}

// ---- fused: gather vmean + 3x (res@W1 -> relu*feats -> @W2 -> relu) + attention ----
// 256 thr = 4 waves, 64 points/block. All fragments loaded direct from global in
// MFMA layout. sH is wave-private -> no __syncthreads anywhere.
__global__ __launch_bounds__(256) void fused_mlp(const float* __restrict__ feats,
                                                 const unsigned short* __restrict__ vmean,
                                                 const int* __restrict__ idx,
                                                 const unsigned short* __restrict__ W1T,
                                                 const unsigned short* __restrict__ W2T,
                                                 const float* __restrict__ b1,
                                                 const float* __restrict__ b2,
                                                 const float* __restrict__ Wa,
                                                 const float* __restrict__ ba,
                                                 float* __restrict__ out) {
    __shared__ __align__(16) unsigned short sH[4][16 * FP];

    int tid = threadIdx.x;
    int wave = tid >> 6, lane = tid & 63;
    int ln = lane & 15, quad = lane >> 4, ko = quad * 8;
    int b0 = blockIdx.x * 64;
    int mrow = wave * 16 + ln;
    int nA = b0 + mrow;
    bool vA = nA < NPTS;

    // A-fragment feats rows (f32), reused across scales
    float fA0[8], fA1[8];
    {
        const float* fr = feats + (size_t)(vA ? nA : 0) * 64;
#pragma unroll
        for (int j = 0; j < 8; ++j) { fA0[j] = fr[ko + j]; fA1[j] = fr[32 + ko + j]; }
    }
    // C-layout feats multipliers (row=wave*16+quad*4+r, col=nt*16+ln)
    float fC[4][4];
#pragma unroll
    for (int r = 0; r < 4; ++r) {
        int n = b0 + wave * 16 + quad * 4 + r;
        const float* fp = feats + (size_t)(n < NPTS ? n : 0) * 64;
#pragma unroll
        for (int nt = 0; nt < 4; ++nt) fC[nt][r] = (n < NPTS) ? fp[nt * 16 + ln] : 0.0f;
    }

    float4v ms[3][4];
    unsigned short* sHw = &sH[wave][0];

    for (int s = 0; s < 3; ++s) {
        // residual A-fragments: res = feats - vmean[gid]  (vmean row = 16B contiguous/lane)
        int g = vA ? idx[(size_t)s * NPTS + nA] : 0;
        const unsigned short* vr = vmean + ((size_t)s * NPTS + g) * 64;
        short8 u0 = *(const short8*)&vr[ko];
        short8 u1 = *(const short8*)&vr[32 + ko];
        short8 a0, a1;
#pragma unroll
        for (int j = 0; j < 8; ++j) {
            float r0 = vA ? fA0[j] - b2f((unsigned short)u0[j]) : 0.0f;
            float r1 = vA ? fA1[j] - b2f((unsigned short)u1[j]) : 0.0f;
            a0[j] = (short)f2b(r0);
            a1[j] = (short)f2b(r1);
        }

        // GEMM1: H = relu(res @ W1 + b1) * feats   (weights direct from global, L1-hot)
#pragma unroll
        for (int nt = 0; nt < 4; ++nt) {
            int ncol = nt * 16 + ln;
            const unsigned short* w1r = W1T + s * 4096 + ncol * 64;
            short8 bb0 = *(const short8*)&w1r[ko];
            short8 bb1 = *(const short8*)&w1r[32 + ko];
            float4v c = {0.f, 0.f, 0.f, 0.f};
            c = __builtin_amdgcn_mfma_f32_16x16x32_bf16(a0, bb0, c, 0, 0, 0);
            c = __builtin_amdgcn_mfma_f32_16x16x32_bf16(a1, bb1, c, 0, 0, 0);
            float bias = b1[s * 64 + ncol];
#pragma unroll
            for (int r = 0; r < 4; ++r) {
                float hv = fmaxf(c[r] + bias, 0.0f) * fC[nt][r];
                sHw[(quad * 4 + r) * FP + ncol] = f2b(hv);
            }
        }
        __threadfence_block();  // order wave-private LDS write -> read (no cross-wave dep)

        // GEMM2: ms = relu(H @ W2 + b2)
        short8 h0 = *(const short8*)&sHw[ln * FP + ko];
        short8 h1 = *(const short8*)&sHw[ln * FP + 32 + ko];
#pragma unroll
        for (int nt = 0; nt < 4; ++nt) {
            int ncol = nt * 16 + ln;
            const unsigned short* w2r = W2T + s * 4096 + ncol * 64;
            short8 bb0 = *(const short8*)&w2r[ko];
            short8 bb1 = *(const short8*)&w2r[32 + ko];
            float4v c = {0.f, 0.f, 0.f, 0.f};
            c = __builtin_amdgcn_mfma_f32_16x16x32_bf16(h0, bb0, c, 0, 0, 0);
            c = __builtin_amdgcn_mfma_f32_16x16x32_bf16(h1, bb1, c, 0, 0, 0);
            float bias2 = b2[s * 64 + ncol];
#pragma unroll
            for (int r = 0; r < 4; ++r) c[r] = fmaxf(c[r] + bias2, 0.0f);
            ms[s][nt] = c;
        }
    }

    // attention: att = sigmoid((ms0+ms1+ms2) @ Wa^T + ba); out = sum_s ms_s * att_s
    float4v sa[4];
#pragma unroll
    for (int nt = 0; nt < 4; ++nt) sa[nt] = ms[0][nt] + ms[1][nt] + ms[2][nt];
    float part[4][3];
#pragma unroll
    for (int r = 0; r < 4; ++r)
#pragma unroll
        for (int sh = 0; sh < 3; ++sh) {
            float p = 0.0f;
#pragma unroll
            for (int nt = 0; nt < 4; ++nt) p += sa[nt][r] * Wa[sh * 64 + nt * 16 + ln];
            part[r][sh] = p;
        }
    for (int m = 1; m < 16; m <<= 1)
#pragma unroll
        for (int r = 0; r < 4; ++r)
#pragma unroll
            for (int sh = 0; sh < 3; ++sh) part[r][sh] += __shfl_xor(part[r][sh], m);
    float att[4][3];
#pragma unroll
    for (int r = 0; r < 4; ++r)
#pragma unroll
        for (int sh = 0; sh < 3; ++sh)
            att[r][sh] = 1.0f / (1.0f + expf(-(part[r][sh] + ba[sh])));

#pragma unroll
    for (int nt = 0; nt < 4; ++nt)
#pragma unroll
        for (int r = 0; r < 4; ++r) {
            int n = b0 + wave * 16 + quad * 4 + r;
            if (n < NPTS) {
                float o = ms[0][nt][r] * att[r][0] + ms[1][nt][r] * att[r][1] +
                          ms[2][nt][r] * att[r][2];
                out[(size_t)n * 64 + nt * 16 + ln] = o;
            }
        }
}

extern "C" void kernel_launch(void* const* d_in, const int* in_sizes, int n_in,
                              void* d_out, int out_size, void* d_ws, size_t ws_size,
                              hipStream_t stream) {
    const float* feats = (const float*)d_in[0];
    const int* coords = (const int*)d_in[1];
    const float* W1 = (const float*)d_in[2];
    const float* b1 = (const float*)d_in[3];
    const float* W2 = (const float*)d_in[4];
    const float* b2 = (const float*)d_in[5];
    const float* Wa = (const float*)d_in[6];
    const float* ba = (const float*)d_in[7];
    float* out = (float*)d_out;

    char* ws = (char*)d_ws;
    size_t o = 0;
    unsigned short* W1T = (unsigned short*)(ws + o); o += 3 * 4096 * 2;
    unsigned short* W2T = (unsigned short*)(ws + o); o += 3 * 4096 * 2;
    o = (o + 255) & ~(size_t)255;
    unsigned short* vmean = (unsigned short*)(ws + o); o += (size_t)3 * NPTS * 64 * 2;
    int* idx = (int*)(ws + o); o += (size_t)3 * NPTS * 4;
    int* next = (int*)(ws + o); o += (size_t)3 * NPTS * 4;
    int* cslot = (int*)(ws + o); o += (size_t)3 * NPTS * 4;
    o = (o + 255) & ~(size_t)255;
    unsigned long long* hKV = (unsigned long long*)(ws + o); o += (size_t)3 * HSIZE * 8;
    int* head = (int*)(ws + o); o += (size_t)3 * HSIZE * 4;  // contiguous with hKV
    int* gctr = (int*)(ws + o); o += 192 * 4;
    // total ~247 MB

    wconv<<<48, 256, 0, stream>>>(W1, W2, W1T, W2T, gctr);
    hipMemsetAsync(hKV, 0xFF, (size_t)3 * HSIZE * 12, stream);  // hKV + head in one memset

    const int BPS = (NPTS + 255) / 256;
    insert3<<<3 * BPS, 256, 0, stream>>>(coords, hKV, head, next, cslot, gctr);
    reduce3<<<(3 * NPTS * 64) / 256, 256, 0, stream>>>(feats, head, next, cslot, gctr, vmean);
    argmax3<<<3 * (NPTS / 32), 256, 0, stream>>>(coords, (const int2*)hKV, idx);
    fused_mlp<<<(NPTS + 63) / 64, 256, 0, stream>>>(feats, vmean, idx, W1T, W2T, b1, b2,
                                                    Wa, ba, out);
}

// Round 5
// 974.767 us; speedup vs baseline: 16.3302x; 1.2158x over previous
//
#include <hip/hip_runtime.h>
#include <hip/hip_bf16.h>
#include <stdint.h>

#define NPTS 500000
#define HSIZE (1u << 20)
#define HMASK (HSIZE - 1)
#define FP 72  // sH row pitch in ushorts: 144B rows -> 16B-aligned b128 reads, 2-way-free banks

typedef __attribute__((ext_vector_type(8))) short short8;
typedef __attribute__((ext_vector_type(4))) float float4v;

__device__ __forceinline__ unsigned short f2b(float f) {
    __hip_bfloat16 h = __float2bfloat16(f);
    return __builtin_bit_cast(unsigned short, h);
}
__device__ __forceinline__ float b2f(unsigned short u) {
    return __builtin_bit_cast(float, ((unsigned)u) << 16);
}

// ---- convert W1, W2 (f32, [s][c][j]) to bf16 transposed [s][j][c]; zero gctr ----
__global__ __launch_bounds__(256) void wconv(const float* __restrict__ W1,
                                             const float* __restrict__ W2,
                                             unsigned short* __restrict__ W1T,
                                             unsigned short* __restrict__ W2T,
                                             int* __restrict__ gctr) {
    int i = blockIdx.x * 256 + threadIdx.x;
    if (i < 192) gctr[i] = 0;
    if (i >= 3 * 4096) return;
    int s = i >> 12, rem = i & 4095, c = rem >> 6, j = rem & 63;
    W1T[s * 4096 + j * 64 + c] = f2b(W1[i]);
    W2T[s * 4096 + j * 64 + c] = f2b(W2[i]);
}

// ---- all 3 scales: 64-bit (key,gid) hash insert + per-slot chain + compact slot list ----
__global__ __launch_bounds__(256) void insert3(const int* __restrict__ coords,
                                               unsigned long long* __restrict__ hKV,
                                               int* __restrict__ head,
                                               int* __restrict__ next,
                                               int* __restrict__ cslot,
                                               int* __restrict__ gctr) {
    const int BPS = (NPTS + 255) / 256;  // 1954
    int s = blockIdx.x / BPS;
    int i = (blockIdx.x % BPS) * 256 + threadIdx.x;
    int shift = s + 1;
    unsigned long long* hs = hKV + (size_t)s * HSIZE;
    int* heads = head + (size_t)s * HSIZE;
    int* nexts = next + (size_t)s * NPTS;
    bool active = i < NPTS;
    unsigned h = 0;
    bool inserted = false;
    if (active) {
        int4 cd = ((const int4*)coords)[i];
        int key = (((cd.w * 512 + (cd.x >> shift)) * 512 + (cd.y >> shift)) * 512 +
                   (cd.z >> shift));
        unsigned long long want = (unsigned long long)(unsigned)key | 0xFFFFFFFF00000000ull;
        h = ((unsigned)key * 2654435761u) >> 12;  // top 20 bits
        while (true) {
            unsigned long long prev = atomicCAS(&hs[h], ~0ull, want);
            if (prev == ~0ull) { inserted = true; break; }
            if ((int)(prev & 0xFFFFFFFFull) == key) break;
            h = (h + 1) & HMASK;
        }
        nexts[i] = atomicExch(&heads[h], i);
    }
    unsigned long long mask = __ballot(inserted);
    if (mask) {
        int lane = threadIdx.x & 63;
        int leader = __ffsll((unsigned long long)mask) - 1;
        int base = 0;
        if (lane == leader) base = atomicAdd(&gctr[s * 64], __popcll(mask));
        base = __shfl(base, leader);
        if (inserted) {
            int gid = base + __popcll(mask & ((1ull << lane) - 1ull));
            ((int*)&hs[h])[1] = gid;  // high word; slot can never be CAS'd again
            cslot[(size_t)s * NPTS + gid] = (int)h;
        }
    }
}

// ---- resolve chain heads into a dense gid-indexed array (removes 2 dependent
// random loads from reduce3's critical path; 1.5M independent threads hide latency)
__global__ __launch_bounds__(256) void headfix3(const int* __restrict__ cslot,
                                                const int* __restrict__ head,
                                                const int* __restrict__ gctr,
                                                int* __restrict__ chead) {
    int t = blockIdx.x * 256 + threadIdx.x;
    int s = t / NPTS;
    if (s >= 3) return;
    int gid = t - s * NPTS;
    if (gid >= gctr[s * 64]) return;
    chead[(size_t)s * NPTS + gid] =
        head[(size_t)s * HSIZE + cslot[(size_t)s * NPTS + gid]];
}

// ---- all 3 scales: 16 lanes per group (4 chains in flight per wave), float4/lane,
// walk chain, exact mean -> bf16 vmean[gid] ----
__global__ __launch_bounds__(256) void reduce3(const float4* __restrict__ feats4,
                                               const int* __restrict__ chead,
                                               const int* __restrict__ next,
                                               const int* __restrict__ gctr,
                                               ushort4* __restrict__ vmean4) {
    int t = blockIdx.x * 256 + threadIdx.x;
    int sub = t >> 4;   // group index over 3*NPTS
    int sl = t & 15;    // sublane: 16 x float4 = 64 channels
    int s = sub / NPTS;
    if (s >= 3) return;
    int gid = sub - s * NPTS;
    if (gid >= gctr[s * 64]) return;
    int i = chead[(size_t)s * NPTS + gid];  // dense coalesced load
    const int* nexts = next + (size_t)s * NPTS;
    float4 sum = {0.f, 0.f, 0.f, 0.f};
    int cnt = 0;
    while (i >= 0) {
        float4 v = feats4[(size_t)i * 16 + sl];  // 256B coalesced row
        int ni = nexts[i];                       // independent of v
        sum.x += v.x; sum.y += v.y; sum.z += v.z; sum.w += v.w;
        cnt++;
        i = ni;
    }
    float cf = (float)cnt;
    ushort4 o;
    o.x = f2b(sum.x / cf);
    o.y = f2b(sum.y / cf);
    o.z = f2b(sum.z / cf);
    o.w = f2b(sum.w / cf);
    vmean4[((size_t)s * NPTS + gid) * 16 + sl] = o;
}

// ---- all 3 scales: 8 corners (8 pts/wave), exact first-max argmax, write winning gid ----
__global__ __launch_bounds__(256) void argmax3(const int* __restrict__ coords,
                                               const int2* __restrict__ hKV,
                                               int* __restrict__ idx) {
    const int PPB = 32;                 // points per block (256 thr / 8 corners)
    const int BPS = NPTS / PPB;         // 15625 exactly
    int s = blockIdx.x / BPS;
    int p = (blockIdx.x % BPS) * PPB + (threadIdx.x >> 3);
    int corner = threadIdx.x & 7;
    int shift = s + 1;
    const int2* hs = hKV + (size_t)s * HSIZE;
    int4 cd = ((const int4*)coords)[p];
    int vx = cd.x >> shift, vy = cd.y >> shift, vz = cd.z >> shift;
    float inv = 1.0f / (float)(1 << shift);
    float fx = (float)(cd.x - (vx << shift)) * inv;  // exact dyadic
    float fy = (float)(cd.y - (vy << shift)) * inv;
    float fz = (float)(cd.z - (vz << shift)) * inv;
    int bx = (corner >> 2) & 1, by = (corner >> 1) & 1, bz = corner & 1;
    float wx = bx ? fx : 1.0f - fx;
    float wy = by ? fy : 1.0f - fy;
    float wz = bz ? fz : 1.0f - fz;
    float w = (wx * wy) * wz;  // same assoc order as jnp.prod
    int key = (((cd.w * 512 + (vx + bx)) * 512 + (vy + by)) * 512 + (vz + bz));
    unsigned h = ((unsigned)key * 2654435761u) >> 12;
    int g = -1;
    while (true) {
        int2 kv = hs[h];                // key + gid in ONE 8B load
        if (kv.x == key) { g = kv.y; break; }
        if (kv.x == -1) break;
        h = (h + 1) & HMASK;
    }
    if (g < 0) w = 0.0f;
    // first-occurrence argmax: strict greater, tie -> smaller corner. xor 1/2/4 stays in group.
    int j = corner;
    for (int m = 1; m < 8; m <<= 1) {
        float ow = __shfl_xor(w, m);
        int oj = __shfl_xor(j, m);
        int og = __shfl_xor(g, m);
        if (ow > w || (ow == w && oj < j)) { w = ow; j = oj; g = og; }
    }
    if (corner == 0) idx[(size_t)s * NPTS + p] = g;
}

// ---- fused: gather vmean + 3x (res@W1 -> relu*feats -> @W2 -> relu) + attention ----
__global__ __launch_bounds__(256) void fused_mlp(const float* __restrict__ feats,
                                                 const unsigned short* __restrict__ vmean,
                                                 const int* __restrict__ idx,
                                                 const unsigned short* __restrict__ W1T,
                                                 const unsigned short* __restrict__ W2T,
                                                 const float* __restrict__ b1,
                                                 const float* __restrict__ b2,
                                                 const float* __restrict__ Wa,
                                                 const float* __restrict__ ba,
                                                 float* __restrict__ out) {
    __shared__ __align__(16) unsigned short sH[4][16 * FP];

    int tid = threadIdx.x;
    int wave = tid >> 6, lane = tid & 63;
    int ln = lane & 15, quad = lane >> 4, ko = quad * 8;
    int b0 = blockIdx.x * 64;
    int mrow = wave * 16 + ln;
    int nA = b0 + mrow;
    bool vA = nA < NPTS;

    // A-fragment feats rows (f32), reused across scales
    float fA0[8], fA1[8];
    {
        const float* fr = feats + (size_t)(vA ? nA : 0) * 64;
#pragma unroll
        for (int j = 0; j < 8; ++j) { fA0[j] = fr[ko + j]; fA1[j] = fr[32 + ko + j]; }
    }
    // C-layout feats multipliers (row=wave*16+quad*4+r, col=nt*16+ln)
    float fC[4][4];
#pragma unroll
    for (int r = 0; r < 4; ++r) {
        int n = b0 + wave * 16 + quad * 4 + r;
        const float* fp = feats + (size_t)(n < NPTS ? n : 0) * 64;
#pragma unroll
        for (int nt = 0; nt < 4; ++nt) fC[nt][r] = (n < NPTS) ? fp[nt * 16 + ln] : 0.0f;
    }

    float4v ms[3][4];
    unsigned short* sHw = &sH[wave][0];

    for (int s = 0; s < 3; ++s) {
        // residual A-fragments: res = feats - vmean[gid]  (vmean row = 16B contiguous/lane)
        int g = vA ? idx[(size_t)s * NPTS + nA] : 0;
        const unsigned short* vr = vmean + ((size_t)s * NPTS + g) * 64;
        short8 u0 = *(const short8*)&vr[ko];
        short8 u1 = *(const short8*)&vr[32 + ko];
        short8 a0, a1;
#pragma unroll
        for (int j = 0; j < 8; ++j) {
            float r0 = vA ? fA0[j] - b2f((unsigned short)u0[j]) : 0.0f;
            float r1 = vA ? fA1[j] - b2f((unsigned short)u1[j]) : 0.0f;
            a0[j] = (short)f2b(r0);
            a1[j] = (short)f2b(r1);
        }

        // GEMM1: H = relu(res @ W1 + b1) * feats   (weights direct from global, L1-hot)
#pragma unroll
        for (int nt = 0; nt < 4; ++nt) {
            int ncol = nt * 16 + ln;
            const unsigned short* w1r = W1T + s * 4096 + ncol * 64;
            short8 bb0 = *(const short8*)&w1r[ko];
            short8 bb1 = *(const short8*)&w1r[32 + ko];
            float4v c = {0.f, 0.f, 0.f, 0.f};
            c = __builtin_amdgcn_mfma_f32_16x16x32_bf16(a0, bb0, c, 0, 0, 0);
            c = __builtin_amdgcn_mfma_f32_16x16x32_bf16(a1, bb1, c, 0, 0, 0);
            float bias = b1[s * 64 + ncol];
#pragma unroll
            for (int r = 0; r < 4; ++r) {
                float hv = fmaxf(c[r] + bias, 0.0f) * fC[nt][r];
                sHw[(quad * 4 + r) * FP + ncol] = f2b(hv);
            }
        }
        __threadfence_block();  // order wave-private LDS write -> read (no cross-wave dep)

        // GEMM2: ms = relu(H @ W2 + b2)
        short8 h0 = *(const short8*)&sHw[ln * FP + ko];
        short8 h1 = *(const short8*)&sHw[ln * FP + 32 + ko];
#pragma unroll
        for (int nt = 0; nt < 4; ++nt) {
            int ncol = nt * 16 + ln;
            const unsigned short* w2r = W2T + s * 4096 + ncol * 64;
            short8 bb0 = *(const short8*)&w2r[ko];
            short8 bb1 = *(const short8*)&w2r[32 + ko];
            float4v c = {0.f, 0.f, 0.f, 0.f};
            c = __builtin_amdgcn_mfma_f32_16x16x32_bf16(h0, bb0, c, 0, 0, 0);
            c = __builtin_amdgcn_mfma_f32_16x16x32_bf16(h1, bb1, c, 0, 0, 0);
            float bias2 = b2[s * 64 + ncol];
#pragma unroll
            for (int r = 0; r < 4; ++r) c[r] = fmaxf(c[r] + bias2, 0.0f);
            ms[s][nt] = c;
        }
    }

    // attention: att = sigmoid((ms0+ms1+ms2) @ Wa^T + ba); out = sum_s ms_s * att_s
    float4v sa[4];
#pragma unroll
    for (int nt = 0; nt < 4; ++nt) sa[nt] = ms[0][nt] + ms[1][nt] + ms[2][nt];
    float part[4][3];
#pragma unroll
    for (int r = 0; r < 4; ++r)
#pragma unroll
        for (int sh = 0; sh < 3; ++sh) {
            float p = 0.0f;
#pragma unroll
            for (int nt = 0; nt < 4; ++nt) p += sa[nt][r] * Wa[sh * 64 + nt * 16 + ln];
            part[r][sh] = p;
        }
    for (int m = 1; m < 16; m <<= 1)
#pragma unroll
        for (int r = 0; r < 4; ++r)
#pragma unroll
            for (int sh = 0; sh < 3; ++sh) part[r][sh] += __shfl_xor(part[r][sh], m);
    float att[4][3];
#pragma unroll
    for (int r = 0; r < 4; ++r)
#pragma unroll
        for (int sh = 0; sh < 3; ++sh)
            att[r][sh] = 1.0f / (1.0f + expf(-(part[r][sh] + ba[sh])));

#pragma unroll
    for (int nt = 0; nt < 4; ++nt)
#pragma unroll
        for (int r = 0; r < 4; ++r) {
            int n = b0 + wave * 16 + quad * 4 + r;
            if (n < NPTS) {
                float o = ms[0][nt][r] * att[r][0] + ms[1][nt][r] * att[r][1] +
                          ms[2][nt][r] * att[r][2];
                out[(size_t)n * 64 + nt * 16 + ln] = o;
            }
        }
}

extern "C" void kernel_launch(void* const* d_in, const int* in_sizes, int n_in,
                              void* d_out, int out_size, void* d_ws, size_t ws_size,
                              hipStream_t stream) {
    const float* feats = (const float*)d_in[0];
    const int* coords = (const int*)d_in[1];
    const float* W1 = (const float*)d_in[2];
    const float* b1 = (const float*)d_in[3];
    const float* W2 = (const float*)d_in[4];
    const float* b2 = (const float*)d_in[5];
    const float* Wa = (const float*)d_in[6];
    const float* ba = (const float*)d_in[7];
    float* out = (float*)d_out;

    char* ws = (char*)d_ws;
    size_t o = 0;
    unsigned short* W1T = (unsigned short*)(ws + o); o += 3 * 4096 * 2;
    unsigned short* W2T = (unsigned short*)(ws + o); o += 3 * 4096 * 2;
    o = (o + 255) & ~(size_t)255;
    unsigned short* vmean = (unsigned short*)(ws + o); o += (size_t)3 * NPTS * 64 * 2;
    int* idx = (int*)(ws + o); o += (size_t)3 * NPTS * 4;
    int* next = (int*)(ws + o); o += (size_t)3 * NPTS * 4;
    int* cslot = (int*)(ws + o); o += (size_t)3 * NPTS * 4;
    int* chead = (int*)(ws + o); o += (size_t)3 * NPTS * 4;
    o = (o + 255) & ~(size_t)255;
    unsigned long long* hKV = (unsigned long long*)(ws + o); o += (size_t)3 * HSIZE * 8;
    int* head = (int*)(ws + o); o += (size_t)3 * HSIZE * 4;  // contiguous with hKV
    int* gctr = (int*)(ws + o); o += 192 * 4;
    // total ~253 MB

    wconv<<<48, 256, 0, stream>>>(W1, W2, W1T, W2T, gctr);
    hipMemsetAsync(hKV, 0xFF, (size_t)3 * HSIZE * 12, stream);  // hKV + head in one memset

    const int BPS = (NPTS + 255) / 256;
    insert3<<<3 * BPS, 256, 0, stream>>>(coords, hKV, head, next, cslot, gctr);
    headfix3<<<(3 * NPTS + 255) / 256, 256, 0, stream>>>(cslot, head, gctr, chead);
    reduce3<<<(3 * NPTS * 16 + 255) / 256, 256, 0, stream>>>((const float4*)feats, chead,
                                                             next, gctr, (ushort4*)vmean);
    argmax3<<<3 * (NPTS / 32), 256, 0, stream>>>(coords, (const int2*)hKV, idx);
    fused_mlp<<<(NPTS + 63) / 64, 256, 0, stream>>>(feats, vmean, idx, W1T, W2T, b1, b2,
                                                    Wa, ba, out);
}